// Round 1
// baseline (275.408 us; speedup 1.0000x reference)
//
#include <hip/hip_runtime.h>

#define TILE 32
#define TS 36   // t halo: tile + 4 (two conv stages)
#define GS 34   // gx/gy/e halo: tile + 2

__global__ __launch_bounds__(256) void nms_loss_kernel(
    const float* __restrict__ tl, const float* __restrict__ pl,
    double* __restrict__ acc_d, float* __restrict__ acc_f,
    int H, int W)
{
    __shared__ float t_s[TS][TS + 1];
    __shared__ float gx_s[GS][GS + 1];
    __shared__ float gy_s[GS][GS + 1];
    __shared__ float e_s[GS][GS + 1];
    __shared__ float wsum[4];

    const int ch = blockIdx.z;
    const int y0 = blockIdx.y * TILE;
    const int x0 = blockIdx.x * TILE;
    const float* tc = tl + (size_t)ch * H * W;
    const float* pc = pl + (size_t)ch * H * W;
    const int tid = threadIdx.x;

    // Stage 1a: true_labels tile, replicate (clamp) padding, coords y0-2..y0+33
    for (int i = tid; i < TS * TS; i += 256) {
        int u = i / TS - 2, w = i % TS - 2;
        int gy = min(max(y0 + u, 0), H - 1);
        int gx = min(max(x0 + w, 0), W - 1);
        t_s[i / TS][i % TS] = tc[gy * W + gx];
    }
    // Stage 1b: e = exp(0.1*pred) tile, reflect (mirror, no edge dup) padding
    for (int i = tid; i < GS * GS; i += 256) {
        int v = i / GS - 1, w = i % GS - 1;
        int gy = y0 + v; gy = gy < 0 ? -gy : (gy >= H ? 2 * H - 2 - gy : gy);
        int gx = x0 + w; gx = gx < 0 ? -gx : (gx >= W ? 2 * W - 2 - gx : gx);
        e_s[i / GS][i % GS] = __expf(0.1f * pc[gy * W + gx]);
    }
    __syncthreads();

    // Stage 2: gx, gy at CLAMPED global coords (first replicate pad), coords y0-1..y0+32
    for (int i = tid; i < GS * GS; i += 256) {
        int v = i / GS - 1, w = i % GS - 1;
        int cy = min(max(y0 + v, 0), H - 1);
        int cx = min(max(x0 + w, 0), W - 1);
        // second-level clamp happens on the GLOBAL coordinate of cy+dy
        int r0 = min(max(cy - 1, 0), H - 1) - y0 + 2;
        int r1 = cy - y0 + 2;
        int r2 = min(max(cy + 1, 0), H - 1) - y0 + 2;
        int c0 = min(max(cx - 1, 0), W - 1) - x0 + 2;
        int c1 = cx - x0 + 2;
        int c2 = min(max(cx + 1, 0), W - 1) - x0 + 2;
        float a00 = t_s[r0][c0], a01 = t_s[r0][c1], a02 = t_s[r0][c2];
        float a10 = t_s[r1][c0],                    a12 = t_s[r1][c2];
        float a20 = t_s[r2][c0], a21 = t_s[r2][c1], a22 = t_s[r2][c2];
        // GX = [[-1,0,1],[-2,0,2],[-1,0,1]]/8 (cross-correlation), GY = GX^T
        gx_s[v + 1][w + 1] = ((a02 - a00) + 2.f * (a12 - a10) + (a22 - a20)) * 0.125f;
        gy_s[v + 1][w + 1] = ((a20 - a00) + 2.f * (a21 - a01) + (a22 - a02)) * 0.125f;
    }
    __syncthreads();

    // Stage 3: per output pixel
    float partial = 0.f;
    for (int i = tid; i < TILE * TILE; i += 256) {
        int v = i / TILE, w = i % TILE;
        float tv = t_s[v + 2][w + 2];
        if (tv > 0.f) {
            int y = y0 + v, x = x0 + w;
            // replicate pad of gx/gy fields (second conv stage)
            int r0 = min(max(y - 1, 0), H - 1) - y0 + 1;
            int r1 = v + 1;
            int r2 = min(max(y + 1, 0), H - 1) - y0 + 1;
            int c0 = min(max(x - 1, 0), W - 1) - x0 + 1;
            int c1 = w + 1;
            int c2 = min(max(x + 1, 0), W - 1) - x0 + 1;
            float gxv00 = gx_s[r0][c0], gxv02 = gx_s[r0][c2];
            float gxv10 = gx_s[r1][c0], gxv12 = gx_s[r1][c2];
            float gxv20 = gx_s[r2][c0], gxv22 = gx_s[r2][c2];
            float gyv00 = gy_s[r0][c0], gyv01 = gy_s[r0][c1], gyv02 = gy_s[r0][c2];
            float gyv10 = gy_s[r1][c0],                        gyv12 = gy_s[r1][c2];
            float gyv20 = gy_s[r2][c0], gyv21 = gy_s[r2][c1], gyv22 = gy_s[r2][c2];

            float grad_xx = ((gxv02 - gxv00) + 2.f * (gxv12 - gxv10) + (gxv22 - gxv20)) * 0.125f;
            float grad_xy = ((gyv02 - gyv00) + 2.f * (gyv12 - gyv10) + (gyv22 - gyv20)) * 0.125f;
            float grad_yy = ((gyv20 - gyv00) + 2.f * (gyv21 - gyv01) + (gyv22 - gyv02)) * 0.125f;

            float sarg = -grad_xy + 1e-7f;
            float s = sarg > 0.f ? 1.f : (sarg < 0.f ? -1.f : 0.f);
            float theta = atanf(grad_yy * s / (grad_xx + 1e-7f));
            float angle = theta * 57.29577951308232f;   // rad -> deg
            if (angle < 0.f) angle += 180.f;

            float ec = e_s[v + 1][w + 1];
            float f;
            bool have = true;
            if (angle < 22.5f || angle >= 157.5f) {          // horizontal
                f = e_s[v + 1][w] + ec + e_s[v + 1][w + 2];
            } else if (angle < 67.5f) {                      // counter-diag (fliplr eye)
                f = e_s[v][w + 2] + ec + e_s[v + 2][w];
            } else if (angle < 112.5f) {                     // vertical
                f = e_s[v][w + 1] + ec + e_s[v + 2][w + 1];
            } else if (angle > 112.5f) {                     // leading diag (eye), angle<157.5 implied
                f = e_s[v][w] + ec + e_s[v + 2][w + 2];
            } else {
                have = false; f = 0.f;                       // angle == 112.5 exactly (or NaN)
            }
            if (have) {
                float r = ec / (f + 1e-7f);
                r = fminf(fmaxf(r, 1e-7f), 1.f);
                partial += __logf(r);
            }
        }
    }

    // Block reduction: wave64 shuffle then cross-wave via LDS
    for (int off = 32; off > 0; off >>= 1)
        partial += __shfl_down(partial, off, 64);
    if ((tid & 63) == 0) wsum[tid >> 6] = partial;
    __syncthreads();
    if (tid == 0) {
        float s = wsum[0] + wsum[1] + wsum[2] + wsum[3];
        if (acc_d) atomicAdd(acc_d, (double)s);
        else       atomicAdd(acc_f, s);
    }
}

__global__ void finalize_kernel(const double* acc_d, const float* acc_f,
                                float* out, int use_double, float inv_b)
{
    double s = use_double ? acc_d[0] : (double)acc_f[0];
    out[0] = (float)(-s * (double)inv_b);
}

extern "C" void kernel_launch(void* const* d_in, const int* in_sizes, int n_in,
                              void* d_out, int out_size, void* d_ws, size_t ws_size,
                              hipStream_t stream)
{
    const float* tl = (const float*)d_in[0];
    const float* pl = (const float*)d_in[1];
    float* out = (float*)d_out;

    const int H = 512, W = 512, B = 4, C = 19;
    const int nch = B * C;

    double* acc_d = nullptr;
    float* acc_f = nullptr;
    int use_double = 0;
    if (ws_size >= sizeof(double)) {
        acc_d = (double*)d_ws;
        use_double = 1;
        hipMemsetAsync(acc_d, 0, sizeof(double), stream);
    } else {
        acc_f = out;
        hipMemsetAsync(out, 0, sizeof(float), stream);
    }

    dim3 grid(W / TILE, H / TILE, nch);
    nms_loss_kernel<<<grid, 256, 0, stream>>>(tl, pl, acc_d, acc_f, H, W);
    finalize_kernel<<<1, 1, 0, stream>>>(acc_d, acc_f ? acc_f : out, out,
                                         use_double, 1.0f / (float)B);
}

// Round 2
// 265.927 us; speedup vs baseline: 1.0357x; 1.0357x over previous
//
#include <hip/hip_runtime.h>

#define TILE 32
#define TS 36   // t halo: tile + 4 (two conv stages)
#define GS 34   // gx/gy/e halo: tile + 2

__global__ __launch_bounds__(256) void nms_loss_kernel(
    const float* __restrict__ tl, const float* __restrict__ pl,
    double* __restrict__ acc_d, float* __restrict__ acc_f,
    int H, int W)
{
    __shared__ float t_s[TS][TS + 1];
    __shared__ float gx_s[GS][GS + 1];
    __shared__ float gy_s[GS][GS + 1];
    __shared__ float e_s[GS][GS + 1];
    __shared__ float wsum[4];

    const int ch = blockIdx.z;
    const int y0 = blockIdx.y * TILE;
    const int x0 = blockIdx.x * TILE;
    const float* tc = tl + (size_t)ch * H * W;
    const float* pc = pl + (size_t)ch * H * W;
    const int tid = threadIdx.x;
    const bool interior = (y0 >= 2) && (y0 + TILE + 2 <= H) &&
                          (x0 >= 2) && (x0 + TILE + 2 <= W);

    if (interior) {
        // fast path: no clamps anywhere
        for (int i = tid; i < TS * TS; i += 256) {
            int u = i / TS, w = i % TS;
            t_s[u][w] = tc[(y0 + u - 2) * W + (x0 + w - 2)];
        }
        for (int i = tid; i < GS * GS; i += 256) {
            int v = i / GS, w = i % GS;
            e_s[v][w] = __expf(0.1f * pc[(y0 + v - 1) * W + (x0 + w - 1)]);
        }
        __syncthreads();
        for (int i = tid; i < GS * GS; i += 256) {
            int v = i / GS, w = i % GS;   // center = t_s[v+1][w+1]
            float a00 = t_s[v][w],     a01 = t_s[v][w + 1],     a02 = t_s[v][w + 2];
            float a10 = t_s[v + 1][w],                          a12 = t_s[v + 1][w + 2];
            float a20 = t_s[v + 2][w], a21 = t_s[v + 2][w + 1], a22 = t_s[v + 2][w + 2];
            gx_s[v][w] = ((a02 - a00) + 2.f * (a12 - a10) + (a22 - a20)) * 0.125f;
            gy_s[v][w] = ((a20 - a00) + 2.f * (a21 - a01) + (a22 - a02)) * 0.125f;
        }
    } else {
        // border path: replicate (t) / reflect (e) at each stage
        for (int i = tid; i < TS * TS; i += 256) {
            int u = i / TS - 2, w = i % TS - 2;
            int gy = min(max(y0 + u, 0), H - 1);
            int gx = min(max(x0 + w, 0), W - 1);
            t_s[i / TS][i % TS] = tc[gy * W + gx];
        }
        for (int i = tid; i < GS * GS; i += 256) {
            int v = i / GS - 1, w = i % GS - 1;
            int gy = y0 + v; gy = gy < 0 ? -gy : (gy >= H ? 2 * H - 2 - gy : gy);
            int gx = x0 + w; gx = gx < 0 ? -gx : (gx >= W ? 2 * W - 2 - gx : gx);
            e_s[i / GS][i % GS] = __expf(0.1f * pc[gy * W + gx]);
        }
        __syncthreads();
        for (int i = tid; i < GS * GS; i += 256) {
            int v = i / GS, w = i % GS;
            int cy = min(max(y0 + v - 1, 0), H - 1);
            int cx = min(max(x0 + w - 1, 0), W - 1);
            // second-level replicate happens on the GLOBAL coord of cy±1
            int r0 = min(max(cy - 1, 0), H - 1) - y0 + 2;
            int r1 = cy - y0 + 2;
            int r2 = min(max(cy + 1, 0), H - 1) - y0 + 2;
            int c0 = min(max(cx - 1, 0), W - 1) - x0 + 2;
            int c1 = cx - x0 + 2;
            int c2 = min(max(cx + 1, 0), W - 1) - x0 + 2;
            float a00 = t_s[r0][c0], a01 = t_s[r0][c1], a02 = t_s[r0][c2];
            float a10 = t_s[r1][c0],                    a12 = t_s[r1][c2];
            float a20 = t_s[r2][c0], a21 = t_s[r2][c1], a22 = t_s[r2][c2];
            gx_s[v][w] = ((a02 - a00) + 2.f * (a12 - a10) + (a22 - a20)) * 0.125f;
            gy_s[v][w] = ((a20 - a00) + 2.f * (a21 - a01) + (a22 - a02)) * 0.125f;
        }
    }
    __syncthreads();

    // Stage 3: per output pixel. gx_s/gy_s[v][w] <-> global (y0+v-1, x0+w-1)
    float partial = 0.f;
    for (int i = tid; i < TILE * TILE; i += 256) {
        int v = i / TILE, w = i % TILE;
        float tv = t_s[v + 2][w + 2];
        if (tv > 0.f) {
            int r0, r2, c0, c2;
            const int r1 = v + 1, c1 = w + 1;
            if (interior) {
                r0 = v; r2 = v + 2; c0 = w; c2 = w + 2;
            } else {
                int y = y0 + v, x = x0 + w;
                r0 = min(max(y - 1, 0), H - 1) - y0 + 1;
                r2 = min(max(y + 1, 0), H - 1) - y0 + 1;
                c0 = min(max(x - 1, 0), W - 1) - x0 + 1;
                c2 = min(max(x + 1, 0), W - 1) - x0 + 1;
            }
            float gxv00 = gx_s[r0][c0], gxv02 = gx_s[r0][c2];
            float gxv10 = gx_s[r1][c0], gxv12 = gx_s[r1][c2];
            float gxv20 = gx_s[r2][c0], gxv22 = gx_s[r2][c2];
            float gyv00 = gy_s[r0][c0], gyv01 = gy_s[r0][c1], gyv02 = gy_s[r0][c2];
            float gyv10 = gy_s[r1][c0],                        gyv12 = gy_s[r1][c2];
            float gyv20 = gy_s[r2][c0], gyv21 = gy_s[r2][c1], gyv22 = gy_s[r2][c2];

            float grad_xx = ((gxv02 - gxv00) + 2.f * (gxv12 - gxv10) + (gxv22 - gxv20)) * 0.125f;
            float grad_xy = ((gyv02 - gyv00) + 2.f * (gyv12 - gyv10) + (gyv22 - gyv20)) * 0.125f;
            float grad_yy = ((gyv20 - gyv00) + 2.f * (gyv21 - gyv01) + (gyv22 - gyv02)) * 0.125f;

            // bucket selection on q = tan(theta); atan is monotonic so no atanf needed
            float sa = 1e-7f - grad_xy;
            float s = sa > 0.f ? 1.f : (sa < 0.f ? -1.f : 0.f);
            float q = __fdividef(grad_yy * s, grad_xx + 1e-7f);
            float aq = fabsf(q);
            bool isH = aq < 0.41421356f;    // tan(22.5 deg)
            bool isV = aq >= 2.41421356f;   // tan(67.5 deg)
            // pair (r1+dy, c1+dx) and (r1-dy, c1-dx):
            //  H:(0,1)  V:(1,0)  CD(q>0):(1,-1)  LD(q<0):(1,1)
            int dy = isH ? 0 : 1;
            int dx = isV ? 0 : (isH ? 1 : (q > 0.f ? -1 : 1));

            float ec = e_s[r1][c1];
            float f = ec + e_s[r1 + dy][c1 + dx] + e_s[r1 - dy][c1 - dx];
            float pv = pc[(y0 + v) * W + (x0 + w)];  // L1-hot: staged just above
            // log(clip(e/(f+eps), eps, 1)) == clamp(0.1*pred - log(f+eps), ln(1e-7), 0)
            float lr = 0.1f * pv - __logf(f + 1e-7f);
            partial += fminf(fmaxf(lr, -16.118095651f), 0.f);
        }
    }

    // Block reduction: wave64 shuffle then cross-wave via LDS
    for (int off = 32; off > 0; off >>= 1)
        partial += __shfl_down(partial, off, 64);
    if ((tid & 63) == 0) wsum[tid >> 6] = partial;
    __syncthreads();
    if (tid == 0) {
        float s = wsum[0] + wsum[1] + wsum[2] + wsum[3];
        if (acc_d) atomicAdd(acc_d, (double)s);
        else       atomicAdd(acc_f, s);
    }
}

__global__ void finalize_kernel(const double* acc_d, const float* acc_f,
                                float* out, int use_double, float inv_b)
{
    double s = use_double ? acc_d[0] : (double)acc_f[0];
    out[0] = (float)(-s * (double)inv_b);
}

extern "C" void kernel_launch(void* const* d_in, const int* in_sizes, int n_in,
                              void* d_out, int out_size, void* d_ws, size_t ws_size,
                              hipStream_t stream)
{
    const float* tl = (const float*)d_in[0];
    const float* pl = (const float*)d_in[1];
    float* out = (float*)d_out;

    const int H = 512, W = 512, B = 4, C = 19;
    const int nch = B * C;

    double* acc_d = nullptr;
    float* acc_f = nullptr;
    int use_double = 0;
    if (ws_size >= sizeof(double)) {
        acc_d = (double*)d_ws;
        use_double = 1;
        hipMemsetAsync(acc_d, 0, sizeof(double), stream);
    } else {
        acc_f = out;
        hipMemsetAsync(out, 0, sizeof(float), stream);
    }

    dim3 grid(W / TILE, H / TILE, nch);
    nms_loss_kernel<<<grid, 256, 0, stream>>>(tl, pl, acc_d, acc_f, H, W);
    finalize_kernel<<<1, 1, 0, stream>>>(acc_d, acc_f ? acc_f : out, out,
                                         use_double, 1.0f / (float)B);
}

// Round 3
// 162.276 us; speedup vs baseline: 1.6972x; 1.6387x over previous
//
#include <hip/hip_runtime.h>

#define TILE 32
#define TS 36   // t halo: tile + 4 (two conv stages)
#define GS 34   // e / gx / gy halo: tile + 2
#define NCH 76  // B*C = 4*19

// smem layout (floats):
//   t_s : [36][40]  local (gy - y0 + 2, gx - x0 + 2)       1440
//   e_s : [34][40]  local (gy - y0 + 1, gx - x0 + 4)       1360
//   gx_s: [34][34]  border only, (gy - y0 + 1, gx - x0 + 1) 1156
//   gy_s: [34][34]  border only                              1156
#define SMEM_FLOATS (1440 + 1360 + 1156 + 1156)

__global__ __launch_bounds__(256) void nms_loss_kernel(
    const float* __restrict__ tl, const float* __restrict__ pl,
    double* __restrict__ acc_d, float* __restrict__ acc_f,
    int H, int W)
{
    __shared__ __align__(16) float smem[SMEM_FLOATS];
    __shared__ float wsum[4];
    float (*t_s)[40] = (float(*)[40])smem;
    float (*e_s)[40] = (float(*)[40])(smem + 1440);
    float (*gx_s)[34] = (float(*)[34])(smem + 2800);
    float (*gy_s)[34] = (float(*)[34])(smem + 3956);

    const int ch = blockIdx.z;
    const int y0 = blockIdx.y * TILE;
    const int x0 = blockIdx.x * TILE;
    const float* tc = tl + (size_t)ch * H * W;
    const float* pc = pl + (size_t)ch * H * W;
    const int tid = threadIdx.x;
    const bool interior = (y0 != 0) && (y0 != H - TILE) &&
                          (x0 != 0) && (x0 != W - TILE);

    float partial = 0.f;

    if (interior) {
        // ---- stage t (scalar, coalesced) ----
        for (int i = tid; i < TS * TS; i += 256) {
            int u = i / TS, w = i % TS;
            t_s[u][w] = tc[(y0 + u - 2) * W + (x0 + w - 2)];
        }
        // ---- stage e = exp(0.1*pred) (float4 loads, cols x0-4 .. x0+35) ----
        for (int i = tid; i < 34 * 10; i += 256) {
            int v = i / 10, c4 = (i % 10) * 4;
            const float4 p4 = *(const float4*)(pc + (y0 + v - 1) * W + (x0 - 4 + c4));
            float4 e4;
            e4.x = __expf(0.1f * p4.x); e4.y = __expf(0.1f * p4.y);
            e4.z = __expf(0.1f * p4.z); e4.w = __expf(0.1f * p4.w);
            *(float4*)&e_s[v][c4] = e4;
        }
        __syncthreads();

        // ---- fused composed 5x5 stencil, 4 px per thread, all in registers ----
        const int r  = tid >> 3;          // 0..31 output row
        const int cs = (tid & 7) << 2;    // 0,4,..,28 output col base

        float a[5][8];
        #pragma unroll
        for (int k = 0; k < 5; ++k) {
            float4 lo = *(const float4*)&t_s[r + k][cs];
            float4 hi = *(const float4*)&t_s[r + k][cs + 4];
            a[k][0] = lo.x; a[k][1] = lo.y; a[k][2] = lo.z; a[k][3] = lo.w;
            a[k][4] = hi.x; a[k][5] = hi.y; a[k][6] = hi.z; a[k][7] = hi.w;
        }
        float V1[8], V2[8], V3[8];
        #pragma unroll
        for (int j = 0; j < 8; ++j) {
            float s04 = a[0][j] + a[4][j];
            float d40 = a[4][j] - a[0][j];
            float s13 = a[1][j] + a[3][j];
            float d31 = a[3][j] - a[1][j];
            V1[j] = s04 + 4.f * s13 + 6.f * a[2][j];   // vert [1,4,6,4,1]
            V3[j] = s04 - 2.f * a[2][j];               // vert [1,0,-2,0,1]
            V2[j] = d40 + 2.f * d31;                   // vert [-1,-2,0,2,1]
        }
        #pragma unroll
        for (int j = 0; j < 4; ++j) {
            float tv = a[2][j + 2];                    // center row, in registers
            if (tv > 0.f) {
                // raw = 64 * grad
                float xx = (V1[j] + V1[j + 4]) - 2.f * V1[j + 2];
                float yy = (V3[j] + V3[j + 4]) + 4.f * (V3[j + 1] + V3[j + 3]) + 6.f * V3[j + 2];
                float xy = (V2[j + 4] - V2[j]) + 2.f * (V2[j + 3] - V2[j + 1]);
                float sa = 6.4e-6f - xy;               // 64 * (1e-7 - grad_xy)
                float s  = sa > 0.f ? 1.f : (sa < 0.f ? -1.f : 0.f);
                float q  = __fdividef(yy * s, xx + 6.4e-6f);
                float aq = fabsf(q);
                bool isH = aq < 0.41421356f;           // tan(22.5)
                bool isV = aq >= 2.41421356f;          // tan(67.5)
                int dy = isH ? 0 : 1;
                int dx = isV ? 0 : (isH ? 1 : (q > 0.f ? -1 : 1));

                int er = r + 1, ecol = cs + j + 4;
                float E = e_s[er][ecol];
                float f = E + e_s[er + dy][ecol + dx] + e_s[er - dy][ecol - dx];
                float pv = pc[(y0 + r) * W + (x0 + cs + j)];   // L1-hot
                float lr = 0.1f * pv - __logf(f + 1e-7f);
                partial += fminf(fmaxf(lr, -16.118095651f), 0.f);
            }
        }
    } else {
        // ================= border path (two-stage, validated in R1) ==========
        for (int i = tid; i < TS * TS; i += 256) {
            int u = i / TS - 2, w = i % TS - 2;
            int gy = min(max(y0 + u, 0), H - 1);
            int gx = min(max(x0 + w, 0), W - 1);
            t_s[i / TS][i % TS] = tc[gy * W + gx];
        }
        // e: reflect pad, local col = global - x0 + 4 (cols 3..36)
        for (int i = tid; i < GS * GS; i += 256) {
            int v = i / GS, w = i % GS;
            int gy = y0 + v - 1; gy = gy < 0 ? -gy : (gy >= H ? 2 * H - 2 - gy : gy);
            int gx = x0 + w - 1; gx = gx < 0 ? -gx : (gx >= W ? 2 * W - 2 - gx : gx);
            e_s[v][w + 3] = __expf(0.1f * pc[gy * W + gx]);
        }
        __syncthreads();
        // stage 2: gx, gy at clamped global coords
        for (int i = tid; i < GS * GS; i += 256) {
            int v = i / GS, w = i % GS;
            int cy = min(max(y0 + v - 1, 0), H - 1);
            int cx = min(max(x0 + w - 1, 0), W - 1);
            int r0 = min(max(cy - 1, 0), H - 1) - y0 + 2;
            int r1 = cy - y0 + 2;
            int r2 = min(max(cy + 1, 0), H - 1) - y0 + 2;
            int c0 = min(max(cx - 1, 0), W - 1) - x0 + 2;
            int c1 = cx - x0 + 2;
            int c2 = min(max(cx + 1, 0), W - 1) - x0 + 2;
            float a00 = t_s[r0][c0], a01 = t_s[r0][c1], a02 = t_s[r0][c2];
            float a10 = t_s[r1][c0],                    a12 = t_s[r1][c2];
            float a20 = t_s[r2][c0], a21 = t_s[r2][c1], a22 = t_s[r2][c2];
            gx_s[v][w] = ((a02 - a00) + 2.f * (a12 - a10) + (a22 - a20)) * 0.125f;
            gy_s[v][w] = ((a20 - a00) + 2.f * (a21 - a01) + (a22 - a02)) * 0.125f;
        }
        __syncthreads();
        // stage 3
        for (int i = tid; i < TILE * TILE; i += 256) {
            int v = i >> 5, w = i & 31;
            float tv = t_s[v + 2][w + 2];
            if (tv > 0.f) {
                int y = y0 + v, x = x0 + w;
                int r0 = min(max(y - 1, 0), H - 1) - y0 + 1;
                int r1 = v + 1;
                int r2 = min(max(y + 1, 0), H - 1) - y0 + 1;
                int c0 = min(max(x - 1, 0), W - 1) - x0 + 1;
                int c1 = w + 1;
                int c2 = min(max(x + 1, 0), W - 1) - x0 + 1;
                float gxv00 = gx_s[r0][c0], gxv02 = gx_s[r0][c2];
                float gxv10 = gx_s[r1][c0], gxv12 = gx_s[r1][c2];
                float gxv20 = gx_s[r2][c0], gxv22 = gx_s[r2][c2];
                float gyv00 = gy_s[r0][c0], gyv01 = gy_s[r0][c1], gyv02 = gy_s[r0][c2];
                float gyv10 = gy_s[r1][c0],                        gyv12 = gy_s[r1][c2];
                float gyv20 = gy_s[r2][c0], gyv21 = gy_s[r2][c1], gyv22 = gy_s[r2][c2];

                float grad_xx = ((gxv02 - gxv00) + 2.f * (gxv12 - gxv10) + (gxv22 - gxv20)) * 0.125f;
                float grad_xy = ((gyv02 - gyv00) + 2.f * (gyv12 - gyv10) + (gyv22 - gyv20)) * 0.125f;
                float grad_yy = ((gyv20 - gyv00) + 2.f * (gyv21 - gyv01) + (gyv22 - gyv02)) * 0.125f;

                float sa = 1e-7f - grad_xy;
                float s = sa > 0.f ? 1.f : (sa < 0.f ? -1.f : 0.f);
                float q = __fdividef(grad_yy * s, grad_xx + 1e-7f);
                float aq = fabsf(q);
                bool isH = aq < 0.41421356f;
                bool isV = aq >= 2.41421356f;
                int dy = isH ? 0 : 1;
                int dx = isV ? 0 : (isH ? 1 : (q > 0.f ? -1 : 1));

                float E = e_s[r1][w + 4];
                float f = E + e_s[r1 + dy][w + 4 + dx] + e_s[r1 - dy][w + 4 - dx];
                float pv = pc[y * W + x];
                float lr = 0.1f * pv - __logf(f + 1e-7f);
                partial += fminf(fmaxf(lr, -16.118095651f), 0.f);
            }
        }
    }

    // ---- block reduction ----
    for (int off = 32; off > 0; off >>= 1)
        partial += __shfl_down(partial, off, 64);
    if ((tid & 63) == 0) wsum[tid >> 6] = partial;
    __syncthreads();
    if (tid == 0) {
        float s = wsum[0] + wsum[1] + wsum[2] + wsum[3];
        if (acc_d) atomicAdd(&acc_d[ch], (double)s);   // per-channel: 76 addresses
        else       atomicAdd(acc_f, s);
    }
}

__global__ void finalize_kernel(const double* acc_d, const float* acc_f,
                                float* out, int use_double, int nch, float inv_b)
{
    if (use_double) {
        double s = 0.0;
        for (int i = 0; i < nch; ++i) s += acc_d[i];
        out[0] = (float)(-s * (double)inv_b);
    } else {
        out[0] = -acc_f[0] * inv_b;
    }
}

extern "C" void kernel_launch(void* const* d_in, const int* in_sizes, int n_in,
                              void* d_out, int out_size, void* d_ws, size_t ws_size,
                              hipStream_t stream)
{
    const float* tl = (const float*)d_in[0];
    const float* pl = (const float*)d_in[1];
    float* out = (float*)d_out;

    const int H = 512, W = 512, B = 4;
    const int nch = NCH;

    double* acc_d = nullptr;
    float* acc_f = nullptr;
    int use_double = 0;
    if (ws_size >= nch * sizeof(double)) {
        acc_d = (double*)d_ws;
        use_double = 1;
        hipMemsetAsync(acc_d, 0, nch * sizeof(double), stream);
    } else {
        acc_f = out;
        hipMemsetAsync(out, 0, sizeof(float), stream);
    }

    dim3 grid(W / TILE, H / TILE, nch);
    nms_loss_kernel<<<grid, 256, 0, stream>>>(tl, pl, acc_d, acc_f, H, W);
    finalize_kernel<<<1, 1, 0, stream>>>(acc_d, acc_f ? acc_f : out, out,
                                         use_double, nch, 1.0f / (float)B);
}

// Round 4
// 154.519 us; speedup vs baseline: 1.7824x; 1.0502x over previous
//
#include <hip/hip_runtime.h>

#define TILE 32
#define NCH 76

// Composed 5-tap weight tables (x64 scaling folded into eps constants).
// Vertical: ss (xx), sd = smooth-outer/diff-inner (xy), dd (yy)
// Horizontal: dd (xx), ds = diff-outer/smooth-inner (xy), ss (yy)

__global__ __launch_bounds__(256, 6) void nms_loss_kernel(
    const float* __restrict__ tl, const float* __restrict__ pl,
    double* __restrict__ acc_d, float* __restrict__ acc_f,
    int H, int W)
{
    __shared__ __align__(16) float t_s[36][40];  // rows y0-2..y0+33, cols x0-2..x0+33 (local col = gx-x0+2)
    __shared__ float e_s[34][41];                // rows y0-1..y0+32, local col = gx-x0+4 (odd stride: conflict-light)
    __shared__ float wsum[4];

    const int ch = blockIdx.z;
    const int y0 = blockIdx.y * TILE, x0 = blockIdx.x * TILE;
    const float* tc = tl + (size_t)ch * H * W;
    const float* pc = pl + (size_t)ch * H * W;
    const int tid = threadIdx.x;
    const bool bint = (y0 != 0) && (y0 != H - TILE) && (x0 != 0) && (x0 != W - TILE);

    if (bint) {
        for (int i = tid; i < 36 * 36; i += 256) {
            int u = i / 36, w = i - u * 36;
            t_s[u][w] = tc[(y0 + u - 2) * W + (x0 + w - 2)];
        }
        for (int i = tid; i < 34 * 10; i += 256) {
            int v = i / 10, c4 = (i - v * 10) * 4;
            float4 p4 = *(const float4*)(pc + (y0 + v - 1) * W + (x0 - 4 + c4));
            e_s[v][c4 + 0] = __expf(0.1f * p4.x);
            e_s[v][c4 + 1] = __expf(0.1f * p4.y);
            e_s[v][c4 + 2] = __expf(0.1f * p4.z);
            e_s[v][c4 + 3] = __expf(0.1f * p4.w);
        }
    } else {
        for (int i = tid; i < 36 * 36; i += 256) {
            int u = i / 36, w = i - u * 36;
            int gy = min(max(y0 + u - 2, 0), H - 1);
            int gx = min(max(x0 + w - 2, 0), W - 1);
            t_s[u][w] = tc[gy * W + gx];
        }
        for (int i = tid; i < 34 * 38; i += 256) {   // local cols 0..37 (need 3..36)
            int v = i / 38, w = i - v * 38;
            int gy = y0 + v - 1; gy = gy < 0 ? -gy : (gy >= H ? 2 * H - 2 - gy : gy);
            int gx = x0 + w - 4; gx = gx < 0 ? -gx : (gx >= W ? 2 * W - 2 - gx : gx);
            e_s[v][w] = __expf(0.1f * pc[gy * W + gx]);
        }
    }
    __syncthreads();

    const int r  = tid >> 3;           // output row 0..31
    const int cs = (tid & 7) << 2;     // output col base 0,4,..,28
    const int y  = y0 + r;

    // ---- vertical composed 5-tap weights (per-thread; constants unless y near edge) ----
    float wss[5], wsd[5], wdd[5];
    if (y >= 2 && y <= H - 3) {
        wss[0]=1; wss[1]=4; wss[2]=6;  wss[3]=4;  wss[4]=1;
        wsd[0]=-1;wsd[1]=-2;wsd[2]=0;  wsd[3]=2;  wsd[4]=1;
        wdd[0]=1; wdd[1]=0; wdd[2]=-2; wdd[3]=0;  wdd[4]=1;
    } else if (y == 0) {
        wss[0]=0; wss[1]=0; wss[2]=10; wss[3]=5;  wss[4]=1;
        wsd[0]=0; wsd[1]=0; wsd[2]=-4; wsd[3]=3;  wsd[4]=1;
        wdd[0]=0; wdd[1]=0; wdd[2]=0;  wdd[3]=-1; wdd[4]=1;
    } else if (y == 1) {
        wss[0]=0; wss[1]=5; wss[2]=6;  wss[3]=4;  wss[4]=1;
        wsd[0]=0; wsd[1]=-3;wsd[2]=0;  wsd[3]=2;  wsd[4]=1;
        wdd[0]=0; wdd[1]=1; wdd[2]=-2; wdd[3]=0;  wdd[4]=1;
    } else if (y == H - 1) {
        wss[0]=1; wss[1]=5; wss[2]=10; wss[3]=0;  wss[4]=0;
        wsd[0]=-1;wsd[1]=-3;wsd[2]=4;  wsd[3]=0;  wsd[4]=0;
        wdd[0]=1; wdd[1]=-1;wdd[2]=0;  wdd[3]=0;  wdd[4]=0;
    } else { // y == H-2
        wss[0]=1; wss[1]=4; wss[2]=6;  wss[3]=5;  wss[4]=0;
        wsd[0]=-1;wsd[1]=-2;wsd[2]=0;  wsd[3]=3;  wsd[4]=0;
        wdd[0]=1; wdd[1]=0; wdd[2]=-2; wdd[3]=1;  wdd[4]=0;
    }

    // ---- vertical pass: row-by-row fma, low register footprint ----
    float V1[8], V2[8], V3[8], mrow[4];
    #pragma unroll
    for (int jj = 0; jj < 8; ++jj) { V1[jj] = 0.f; V2[jj] = 0.f; V3[jj] = 0.f; }
    #pragma unroll
    for (int k = 0; k < 5; ++k) {
        float4 lo = *(const float4*)&t_s[r + k][cs];
        float4 hi = *(const float4*)&t_s[r + k][cs + 4];
        float row[8] = {lo.x, lo.y, lo.z, lo.w, hi.x, hi.y, hi.z, hi.w};
        #pragma unroll
        for (int jj = 0; jj < 8; ++jj) {
            V1[jj] = fmaf(wss[k], row[jj], V1[jj]);
            V2[jj] = fmaf(wsd[k], row[jj], V2[jj]);
            V3[jj] = fmaf(wdd[k], row[jj], V3[jj]);
        }
        if (k == 2) { mrow[0] = row[2]; mrow[1] = row[3]; mrow[2] = row[4]; mrow[3] = row[5]; }
    }

    // ---- horizontal pass per pixel ----
    float xx4[4], xy4[4], yy4[4];
    #pragma unroll
    for (int j = 0; j < 4; ++j) {
        int x = x0 + cs + j;
        float xx, xy, yy;
        if (x >= 2 && x <= W - 3) {
            xx = (V1[j] + V1[j + 4]) - 2.f * V1[j + 2];
            xy = (V2[j + 4] - V2[j]) + 2.f * (V2[j + 3] - V2[j + 1]);
            yy = (V3[j] + V3[j + 4]) + 4.f * (V3[j + 1] + V3[j + 3]) + 6.f * V3[j + 2];
        } else {
            float hdd[5], hds[5], hss[5];
            if (x == 0) {
                hdd[0]=0; hdd[1]=0;  hdd[2]=0;  hdd[3]=-1; hdd[4]=1;
                hds[0]=0; hds[1]=0;  hds[2]=-2; hds[3]=1;  hds[4]=1;
                hss[0]=0; hss[1]=0;  hss[2]=10; hss[3]=5;  hss[4]=1;
            } else if (x == 1) {
                hdd[0]=0; hdd[1]=1;  hdd[2]=-2; hdd[3]=0;  hdd[4]=1;
                hds[0]=0; hds[1]=-3; hds[2]=0;  hds[3]=2;  hds[4]=1;
                hss[0]=0; hss[1]=5;  hss[2]=6;  hss[3]=4;  hss[4]=1;
            } else if (x == W - 1) {
                hdd[0]=1; hdd[1]=-1; hdd[2]=0;  hdd[3]=0;  hdd[4]=0;
                hds[0]=-1;hds[1]=-1; hds[2]=2;  hds[3]=0;  hds[4]=0;
                hss[0]=1; hss[1]=5;  hss[2]=10; hss[3]=0;  hss[4]=0;
            } else { // x == W-2
                hdd[0]=1; hdd[1]=0;  hdd[2]=-2; hdd[3]=1;  hdd[4]=0;
                hds[0]=-1;hds[1]=-2; hds[2]=0;  hds[3]=3;  hds[4]=0;
                hss[0]=1; hss[1]=4;  hss[2]=6;  hss[3]=5;  hss[4]=0;
            }
            xx = 0.f; xy = 0.f; yy = 0.f;
            #pragma unroll
            for (int m = 0; m < 5; ++m) {
                xx = fmaf(hdd[m], V1[j + m], xx);
                xy = fmaf(hds[m], V2[j + m], xy);
                yy = fmaf(hss[m], V3[j + m], yy);
            }
        }
        xx4[j] = xx; xy4[j] = xy; yy4[j] = yy;
    }

    // ---- tail: early unconditional e loads, branch-free select, log ----
    float partial = 0.f;
    const int er = r + 1;
    const float4 pv4 = *(const float4*)(pc + (size_t)y * W + x0 + cs);
    #pragma unroll
    for (int h = 0; h < 2; ++h) {
        const int b = cs + 3 + 2 * h;   // e cols b..b+3 cover this half's centers +-1
        float e0[4], e1[4], e2[4];
        #pragma unroll
        for (int q = 0; q < 4; ++q) {
            e0[q] = e_s[er - 1][b + q];
            e1[q] = e_s[er    ][b + q];
            e2[q] = e_s[er + 1][b + q];
        }
        #pragma unroll
        for (int jj = 0; jj < 2; ++jj) {
            const int j = 2 * h + jj;
            if (mrow[j] > 0.f) {
                float xx = xx4[j], xy = xy4[j], yy = yy4[j];   // 64x scaled
                float sa = 6.4e-6f - xy;                        // 64*(1e-7 - grad_xy)
                float s  = sa > 0.f ? 1.f : (sa < 0.f ? -1.f : 0.f);
                float q  = __fdividef(yy * s, xx + 6.4e-6f);
                float aq = fabsf(q);
                bool isH = aq < 0.41421356f;    // tan(22.5)
                bool isV = aq >= 2.41421356f;   // tan(67.5)
                const int qc = jj + 1;
                float E  = e1[qc];
                float dn = q > 0.f ? e2[qc - 1] : e2[qc + 1];
                float n1 = isH ? e1[qc + 1] : (isV ? e2[qc] : dn);
                float up = q > 0.f ? e0[qc + 1] : e0[qc - 1];
                float n2 = isH ? e1[qc - 1] : (isV ? e0[qc] : up);
                float f  = E + n1 + n2;
                float pv = (j == 0) ? pv4.x : (j == 1) ? pv4.y : (j == 2) ? pv4.z : pv4.w;
                float lr = 0.1f * pv - __logf(f + 1e-7f);
                partial += fminf(fmaxf(lr, -16.118095651f), 0.f);
            }
        }
    }

    // ---- block reduction ----
    for (int off = 32; off > 0; off >>= 1)
        partial += __shfl_down(partial, off, 64);
    if ((tid & 63) == 0) wsum[tid >> 6] = partial;
    __syncthreads();
    if (tid == 0) {
        float s = wsum[0] + wsum[1] + wsum[2] + wsum[3];
        if (acc_d) atomicAdd(&acc_d[ch], (double)s);
        else       atomicAdd(acc_f, s);
    }
}

__global__ void finalize_kernel(const double* acc_d, const float* acc_f,
                                float* out, int use_double, int nch, float inv_b)
{
    if (use_double) {
        double s = 0.0;
        for (int i = 0; i < nch; ++i) s += acc_d[i];
        out[0] = (float)(-s * (double)inv_b);
    } else {
        out[0] = -acc_f[0] * inv_b;
    }
}

extern "C" void kernel_launch(void* const* d_in, const int* in_sizes, int n_in,
                              void* d_out, int out_size, void* d_ws, size_t ws_size,
                              hipStream_t stream)
{
    const float* tl = (const float*)d_in[0];
    const float* pl = (const float*)d_in[1];
    float* out = (float*)d_out;

    const int H = 512, W = 512, B = 4;
    const int nch = NCH;

    double* acc_d = nullptr;
    float* acc_f = nullptr;
    int use_double = 0;
    if (ws_size >= nch * sizeof(double)) {
        acc_d = (double*)d_ws;
        use_double = 1;
        hipMemsetAsync(acc_d, 0, nch * sizeof(double), stream);
    } else {
        acc_f = out;
        hipMemsetAsync(out, 0, sizeof(float), stream);
    }

    dim3 grid(W / TILE, H / TILE, nch);
    nms_loss_kernel<<<grid, 256, 0, stream>>>(tl, pl, acc_d, acc_f, H, W);
    finalize_kernel<<<1, 1, 0, stream>>>(acc_d, acc_f ? acc_f : out, out,
                                         use_double, nch, 1.0f / (float)B);
}